// Round 15
// baseline (308.397 us; speedup 1.0000x reference)
//
#include <hip/hip_runtime.h>
#include <stdint.h>

// MultiHeadAttention: B=2, S=2048, D=1024, H=16, dh=64
// d_out = [ out f32 (2*2048*1024) | attn f32 (2*16*2048*2048) ]
// vs best (257.9us R13): ONE change — attn stores are PLAIN f32x4 instead of
// nontemporal. With the 256B-contiguous lane mapping every store is a FULL
// 128B line -> no read-for-ownership (R8's plain-store loss used the old 64B
// partial-line mapping). All loads are NORMAL cached loads (R14's nt-load
// experiment caused stale reads across graph replays and is fully reverted).
// ws (f16 elements):
//   Xq 0, Xk 4194304, Xv 8388608         (converted inputs)
//   Wt 12582912 (Wq^T,Wk^T,Wv^T,Wo^T, 1048576 each)
//   Qb 16777216, Kb 20971520             ([bh][s][64])
//   Vt 25165824                          ([bh][d][2048])
//   ctx 29360128                         ([m][1024])

typedef _Float16 f16;
typedef f16 f16x4 __attribute__((ext_vector_type(4)));
typedef f16 f16x8 __attribute__((ext_vector_type(8)));
typedef float f32x4 __attribute__((ext_vector_type(4)));
typedef uint32_t u32;
typedef u32 u32x4 __attribute__((ext_vector_type(4)));

#define L2E 1.4426950408889634f

__device__ __forceinline__ void gload16(const void* g, void* l) {
    __builtin_amdgcn_global_load_lds((__attribute__((address_space(1))) void*)g,
                                     (__attribute__((address_space(3))) void*)l,
                                     16, 0, 0);
}

// ---------------- convert inputs f32 -> f16 ----------------
__global__ __launch_bounds__(256) void k_cvt(const float* __restrict__ q,
                                             const float* __restrict__ k,
                                             const float* __restrict__ v,
                                             f16* __restrict__ dst)
{
    int z = blockIdx.z;
    const float* s = (z == 0) ? q : (z == 1) ? k : v;
    size_t i = (size_t)blockIdx.x * 256 + threadIdx.x;   // 0..1048575
    float4 f = ((const float4*)s)[i];
    f16x4 o = {(f16)f.x, (f16)f.y, (f16)f.z, (f16)f.w};
    *(f16x4*)(dst + (size_t)z * 4194304 + i * 4) = o;
}

// ---------------- weight transpose+convert: W[k][n] f32 -> Wt[n][k] f16 ----------------
__global__ __launch_bounds__(256) void k_wtrans(const float* __restrict__ w0,
                                                const float* __restrict__ w1,
                                                const float* __restrict__ w2,
                                                const float* __restrict__ w3,
                                                f16* __restrict__ wt)
{
    __shared__ f16 t[64][72];   // [n][k], padded
    int z = blockIdx.z;
    const float* W = (z == 0) ? w0 : (z == 1) ? w1 : (z == 2) ? w2 : w3;
    f16* outp = wt + (size_t)z * 1048576;
    int tx = blockIdx.x, ty = blockIdx.y, tid = threadIdx.x;
#pragma unroll
    for (int r4 = 0; r4 < 4; r4++) {
        int row = r4 * 16 + (tid >> 4);      // k local
        int col = (tid & 15) * 4;            // n local
        float4 f = *(const float4*)(W + (size_t)(ty * 64 + row) * 1024 + tx * 64 + col);
        t[col + 0][row] = (f16)f.x; t[col + 1][row] = (f16)f.y;
        t[col + 2][row] = (f16)f.z; t[col + 3][row] = (f16)f.w;
    }
    __syncthreads();
#pragma unroll
    for (int cc = 0; cc < 2; cc++) {
        int c = tid + cc * 256;
        int row = c >> 3, ch = c & 7;        // n local, 8-elem chunk of k
        f16x8 vv;
#pragma unroll
        for (int j = 0; j < 8; j++) vv[j] = t[row][ch * 8 + j];
        *(f16x8*)(outp + (size_t)(tx * 64 + row) * 1024 + ty * 64 + ch * 8) = vv;
    }
}

// ---------------- GEMM: C[M=4096][N=1024] = A[m][k] * Bt[n][k]^T + bias ----------------
__global__ __launch_bounds__(256) void k_gemm(const f16* __restrict__ Ab,
                                              const f16* __restrict__ Wtb,
                                              const float* __restrict__ b0,
                                              const float* __restrict__ b1,
                                              const float* __restrict__ b2,
                                              void* __restrict__ o0,
                                              void* __restrict__ o1,
                                              int proj)
{
    __shared__ __align__(16) char As[16384];  // [128 rows][128B = BK=64 f16]
    __shared__ __align__(16) char Bs[16384];
    const int tid = threadIdx.x;
    const int wv = tid >> 6, ln = tid & 63, lg = ln >> 4, li = ln & 15;
    const int m0 = blockIdx.y * 128, n0 = blockIdx.x * 128;
    const int wm = (wv >> 1) * 64, wn = (wv & 1) * 64;

    const f16* A; const f16* Bt; const float* bias; int mode;
    if (proj) {
        int z = blockIdx.z;
        A = Ab + (size_t)z * 4194304;
        Bt = Wtb + (size_t)z * 1048576;
        bias = (z == 0) ? b0 : (z == 1) ? b1 : b2;
        mode = (z == 2) ? 1 : 0;
    } else { A = Ab; Bt = Wtb; bias = b0; mode = 2; }

    const char* gA[4]; const char* gB[4];
#pragma unroll
    for (int c = 0; c < 4; c++) {
        int r = (wv * 4 + c) * 8 + (ln >> 3);
        int j = (ln & 7) ^ (r & 7);
        gA[c] = (const char*)A  + (size_t)(m0 + r) * 2048 + j * 16;
        gB[c] = (const char*)Bt + (size_t)(n0 + r) * 2048 + j * 16;
    }

    f32x4 acc[4][4] = {};
    for (int kt = 0; kt < 16; kt++) {
        __syncthreads();
#pragma unroll
        for (int c = 0; c < 4; c++) {
            gload16(gA[c] + kt * 128, As + (wv * 4 + c) * 1024);
            gload16(gB[c] + kt * 128, Bs + (wv * 4 + c) * 1024);
        }
        __syncthreads();
#pragma unroll
        for (int kk = 0; kk < 2; kk++) {
            f16x8 af[4], bf[4];
#pragma unroll
            for (int mi = 0; mi < 4; mi++) {
                int row = wm + mi * 16 + li;
                af[mi] = *(const f16x8*)(As + row * 128 + (((kk * 4 + lg) ^ (row & 7)) * 16));
            }
#pragma unroll
            for (int ni = 0; ni < 4; ni++) {
                int row = wn + ni * 16 + li;
                bf[ni] = *(const f16x8*)(Bs + row * 128 + (((kk * 4 + lg) ^ (row & 7)) * 16));
            }
#pragma unroll
            for (int mi = 0; mi < 4; mi++)
#pragma unroll
                for (int ni = 0; ni < 4; ni++)
                    acc[mi][ni] = __builtin_amdgcn_mfma_f32_16x16x32_f16(af[mi], bf[ni], acc[mi][ni], 0, 0, 0);
        }
    }

    float bvs[4];
#pragma unroll
    for (int ni = 0; ni < 4; ni++) bvs[ni] = bias[n0 + wn + ni * 16 + li];

    if (mode == 2) {
        float* O = (float*)o0;
#pragma unroll
        for (int mi = 0; mi < 4; mi++)
#pragma unroll
            for (int ni = 0; ni < 4; ni++) {
                int n = n0 + wn + ni * 16 + li;
#pragma unroll
                for (int r = 0; r < 4; r++) {
                    int m = m0 + wm + mi * 16 + lg * 4 + r;
                    O[(size_t)m * 1024 + n] = acc[mi][ni][r] + bvs[ni];
                }
            }
    } else if (mode == 0) {
        f16* O = (f16*)o0 + (size_t)blockIdx.z * 4194304;  // Qb or Kb
#pragma unroll
        for (int mi = 0; mi < 4; mi++)
#pragma unroll
            for (int ni = 0; ni < 4; ni++) {
                int n = n0 + wn + ni * 16 + li;
                int h = n >> 6, d = n & 63;
#pragma unroll
                for (int r = 0; r < 4; r++) {
                    int m = m0 + wm + mi * 16 + lg * 4 + r;
                    int b = m >> 11, s = m & 2047;
                    O[(((size_t)b * 16 + h) * 2048 + s) * 64 + d] = (f16)(acc[mi][ni][r] + bvs[ni]);
                }
            }
    } else {
        f16* O = (f16*)o1;  // Vt [bh][d][2048]
#pragma unroll
        for (int mi = 0; mi < 4; mi++)
#pragma unroll
            for (int ni = 0; ni < 4; ni++) {
                int n = n0 + wn + ni * 16 + li;
                int h = n >> 6, d = n & 63;
                int mb = m0 + wm + mi * 16 + lg * 4;
                int b = mb >> 11, s = mb & 2047;
                f16x4 pk;
#pragma unroll
                for (int r = 0; r < 4; r++) pk[r] = (f16)(acc[mi][ni][r] + bvs[ni]);
                *(f16x4*)(O + (((size_t)b * 16 + h) * 64 + d) * 2048 + s) = pk;
            }
    }
}

// ---------------- attention (R13 structure; PLAIN full-line 256B-segment stores) ----------------
// grid 1024 x 256 thr (4 waves, wave owns 16 q rows).
// bh = (bid&7)*4 + ((bid>>3)>>5): each XCD owns 4 heads (K+V 2MB).
// Pass 1: K staged in LDS, 128-kv tiles, l-sum only (no stores).
// Pass 2: K staged in LDS (64-kv, swizzled, depth-1 reg prefetch); V direct
// from L2/L3 (cached loads); P -> wave-private LDS (f16, for PV); attn read
// back in transposed lane mapping -> PLAIN f32x4 stores, 4 rows x 256B
// contiguous = full 128B lines (write-back via L2, no RFO).
// Swapped QK^T: z = mfma(K,Q) -> lane holds P^T[kv][q], q=li lane-local.
__global__ __launch_bounds__(256, 4) void k_attn(const f16* __restrict__ Qb,
                                                 const f16* __restrict__ Kb,
                                                 const f16* __restrict__ Vt,
                                                 float* __restrict__ attn,
                                                 f16* __restrict__ ctx)
{
    __shared__ __align__(16) char Ks[16384];     // pass1: [128 kv][64 d]; pass2: [64 kv][64 d]
    __shared__ __align__(16) char Ps[4][2048];   // per-wave P [16 q][64 kv] f16, chunk^(row&7)
    const int tid = threadIdx.x, wv = tid >> 6, ln = tid & 63, lg = ln >> 4, li = ln & 15;
    const int bid = blockIdx.x;
    const int kk = bid >> 3;
    const int bh = (bid & 7) * 4 + (kk >> 5);
    const int q0 = (kk & 31) * 64 + wv * 16;

    const char* KbB = (const char*)Kb + (size_t)bh * 262144;  // 2048 kv x 128B
    const char* VtB = (const char*)Vt + (size_t)bh * 262144;  // 64 d x 4096B

    // Q fragment (B-operand), rows q0+li, scaled by 1/sqrt(64)
    const f16* qrow = Qb + ((size_t)bh * 2048 + q0 + li) * 64 + lg * 8;
    f16x8 aq0 = *(const f16x8*)(qrow);
    f16x8 aq1 = *(const f16x8*)(qrow + 32);
#pragma unroll
    for (int j = 0; j < 8; j++) {
        aq0[j] = (f16)((float)aq0[j] * 0.125f);
        aq1[j] = (f16)((float)aq1[j] * 0.125f);
    }

    // ================= pass 1: row sum of exp (128-kv tiles) =================
    float lacc[4] = {0.f, 0.f, 0.f, 0.f};
    {
        int swp[4];
        const char* gp[4];
#pragma unroll
        for (int t = 0; t < 4; t++) {
            int c = tid + t * 256;
            int r = c >> 3, j = c & 7;
            swp[t] = r * 128 + ((j ^ (r & 7)) * 16);
            gp[t] = KbB + (size_t)r * 128 + j * 16;
        }
        u32x4 s[4];
#pragma unroll
        for (int t = 0; t < 4; t++) s[t] = *(const u32x4*)(gp[t]);
        for (int kt = 0; kt < 16; kt++) {
            __syncthreads();
#pragma unroll
            for (int t = 0; t < 4; t++) *(u32x4*)(Ks + swp[t]) = s[t];
            __syncthreads();
            if (kt + 1 < 16) {
#pragma unroll
                for (int t = 0; t < 4; t++) s[t] = *(const u32x4*)(gp[t] + (size_t)(kt + 1) * 16384);
            }
#pragma unroll
            for (int cf = 0; cf < 8; cf++) {
                int row = cf * 16 + li;
                f16x8 ak0 = *(const f16x8*)(Ks + row * 128 + ((lg ^ (row & 7)) * 16));
                f16x8 ak1 = *(const f16x8*)(Ks + row * 128 + (((4 + lg) ^ (row & 7)) * 16));
                f32x4 z = {0.f, 0.f, 0.f, 0.f};
                z = __builtin_amdgcn_mfma_f32_16x16x32_f16(ak0, aq0, z, 0, 0, 0);
                z = __builtin_amdgcn_mfma_f32_16x16x32_f16(ak1, aq1, z, 0, 0, 0);
                lacc[cf & 3] += exp2f(z[0] * L2E) + exp2f(z[1] * L2E)
                              + exp2f(z[2] * L2E) + exp2f(z[3] * L2E);
            }
        }
    }
    float l_ = (lacc[0] + lacc[1]) + (lacc[2] + lacc[3]);
    l_ += __shfl_xor(l_, 16);
    l_ += __shfl_xor(l_, 32);
    const float inv_l = 1.0f / l_;
    float* aBase = attn + ((size_t)bh * 2048 + q0) * 2048;
    char* Pw = Ps[wv];

    // coalesced store lane mapping (constant over kt):
    //   instruction j: row = j*4 + (ln>>4), kv = (ln&15)*4
    const int srowb = ln >> 4;                 // 0..3
    const int skv = (ln & 15) * 4;             // 0..60
    const int sldso = (((ln & 15) >> 1) * 16) + (ln & 1) * 8;  // chunk*16 + half

    // ================= pass 2: P, attn out, PV (64-kv tiles) =================
    f32x4 cacc[4] = {};   // ctx^T frags: q=li, d=df*16+lg*4+r
    const int r0 = tid >> 3, j0 = tid & 7;
    const int r1 = (tid + 256) >> 3, j1 = (tid + 256) & 7;
    const int sw0 = r0 * 128 + ((j0 ^ (r0 & 7)) * 16);
    const int sw1 = r1 * 128 + ((j1 ^ (r1 & 7)) * 16);
    u32x4 sk0 = *(const u32x4*)(KbB + (size_t)r0 * 128 + j0 * 16);
    u32x4 sk1 = *(const u32x4*)(KbB + (size_t)r1 * 128 + j1 * 16);
    for (int kt = 0; kt < 32; kt++) {
        __syncthreads();
        *(u32x4*)(Ks + sw0) = sk0;
        *(u32x4*)(Ks + sw1) = sk1;
        __syncthreads();
        if (kt + 1 < 32) {
            sk0 = *(const u32x4*)(KbB + (size_t)((kt + 1) * 64 + r0) * 128 + j0 * 16);
            sk1 = *(const u32x4*)(KbB + (size_t)((kt + 1) * 64 + r1) * 128 + j1 * 16);
        }
        // V fragments direct from global (cached; issued early, hides under QK^T)
        f16x8 vf[4][2];
#pragma unroll
        for (int df = 0; df < 4; df++) {
            const char* vr = VtB + (size_t)(df * 16 + li) * 4096 + kt * 128 + lg * 16;
            vf[df][0] = *(const f16x8*)vr;
            vf[df][1] = *(const f16x8*)(vr + 64);
        }
        // QK^T from LDS
        f32x4 zz[4];
#pragma unroll
        for (int cf = 0; cf < 4; cf++) {
            int row = cf * 16 + li;
            f16x8 ak0 = *(const f16x8*)(Ks + row * 128 + ((lg ^ (row & 7)) * 16));
            f16x8 ak1 = *(const f16x8*)(Ks + row * 128 + (((4 + lg) ^ (row & 7)) * 16));
            f32x4 z = {0.f, 0.f, 0.f, 0.f};
            z = __builtin_amdgcn_mfma_f32_16x16x32_f16(ak0, aq0, z, 0, 0, 0);
            z = __builtin_amdgcn_mfma_f32_16x16x32_f16(ak1, aq1, z, 0, 0, 0);
            zz[cf] = z;
        }
        // exp -> P pack into wave-private LDS (f16, swizzled)
#pragma unroll
        for (int cf = 0; cf < 4; cf++) {
            float p0 = exp2f(zz[cf][0] * L2E) * inv_l;
            float p1 = exp2f(zz[cf][1] * L2E) * inv_l;
            float p2 = exp2f(zz[cf][2] * L2E) * inv_l;
            float p3 = exp2f(zz[cf][3] * L2E) * inv_l;
            f16x4 pk = {(f16)p0, (f16)p1, (f16)p2, (f16)p3};
            int c = cf * 2 + (lg >> 1);
            *(f16x4*)(Pw + li * 128 + ((c ^ (li & 7)) * 16) + (lg & 1) * 8) = pk;
        }
        // attn store: LDS readback in transposed lane mapping -> PLAIN f32x4,
        // 4 rows x 256B contiguous = full 128B lines (write-back via L2)
#pragma unroll
        for (int j = 0; j < 4; j++) {
            int row = j * 4 + srowb;
            f16x4 pv4 = *(const f16x4*)(Pw + row * 128 + (sldso ^ ((row & 7) * 16)));
            f32x4 fv = {(float)pv4[0], (float)pv4[1], (float)pv4[2], (float)pv4[3]};
            *(f32x4*)(aBase + (size_t)row * 2048 + kt * 64 + skv) = fv;
        }
        // PV: ctx^T += V^T * P^T
#pragma unroll
        for (int s2 = 0; s2 < 2; s2++) {
            f16x8 bp = *(const f16x8*)(Pw + li * 128 + (((s2 * 4 + lg) ^ (li & 7)) * 16));
#pragma unroll
            for (int df = 0; df < 4; df++)
                cacc[df] = __builtin_amdgcn_mfma_f32_16x16x32_f16(vf[df][s2], bp, cacc[df], 0, 0, 0);
        }
    }

    // ctx write: [m = b*2048+s][n = h*64+d]
    const int b = bh >> 4, h = bh & 15;
#pragma unroll
    for (int df = 0; df < 4; df++) {
        f16x4 pk;
#pragma unroll
        for (int r = 0; r < 4; r++) pk[r] = (f16)cacc[df][r];
        size_t mrow = (size_t)b * 2048 + q0 + li;
        size_t n = (size_t)h * 64 + df * 16 + lg * 4;
        *(f16x4*)(ctx + mrow * 1024 + n) = pk;
    }
}

extern "C" void kernel_launch(void* const* d_in, const int* in_sizes, int n_in,
                              void* d_out, int out_size, void* d_ws, size_t ws_size,
                              hipStream_t stream)
{
    const float* q  = (const float*)d_in[0];
    const float* k  = (const float*)d_in[1];
    const float* v  = (const float*)d_in[2];
    const float* Wq = (const float*)d_in[3];
    const float* bq = (const float*)d_in[4];
    const float* Wk = (const float*)d_in[5];
    const float* bk = (const float*)d_in[6];
    const float* Wv = (const float*)d_in[7];
    const float* bv = (const float*)d_in[8];
    const float* Wo = (const float*)d_in[9];
    const float* bo = (const float*)d_in[10];

    f16* W = (f16*)d_ws;
    float* out = (float*)d_out;
    float* attn = out + 4194304;

    f16* X   = W;                 // 3 x 4194304
    f16* Wt  = W + 12582912;      // 4 x 1048576
    f16* QKb = W + 16777216;      // Qb then Kb
    f16* Vt  = W + 25165824;
    f16* ctx = W + 29360128;

    k_cvt<<<dim3(4096, 1, 3), 256, 0, stream>>>(q, k, v, X);
    k_wtrans<<<dim3(16, 16, 4), 256, 0, stream>>>(Wq, Wk, Wv, Wo, Wt);
    k_gemm<<<dim3(8, 32, 3), 256, 0, stream>>>(X, Wt, bq, bk, bv, QKb, Vt, 1);
    k_attn<<<dim3(1024), 256, 0, stream>>>(QKb, QKb + 4194304, Vt, attn, ctx);
    k_gemm<<<dim3(8, 32, 1), 256, 0, stream>>>(ctx, Wt + 3145728, bo, bo, bo, out, nullptr, 0);
}

// Round 16
// 253.331 us; speedup vs baseline: 1.2174x; 1.2174x over previous
//
#include <hip/hip_runtime.h>
#include <stdint.h>

// MultiHeadAttention: B=2, S=2048, D=1024, H=16, dh=64
// d_out = [ out f32 (2*2048*1024) | attn f32 (2*16*2048*2048) ]
// vs best (257.9us R13): attn kernel UNTOUCHED (nt 256B-segment stores,
// (256,4)). Chain changes only:
//  (1) k_cvt + k_wtrans merged into one k_prep launch,
//  (2) k_gemm XCD-bijective block swizzle (XCD owns 4 m-rows x 8 n-cols:
//      A 1MB + B 2MB < 4MB L2),
//  (3) 1/sqrt(64) folded into Wq/bq at prep: attn drops its Q rescale loop.
// ws (f16 elements):
//   Xq 0, Xk 4194304, Xv 8388608         (converted inputs)
//   Wt 12582912 (Wq^T*0.125,Wk^T,Wv^T,Wo^T, 1048576 each)
//   Qb 16777216, Kb 20971520             ([bh][s][64])
//   Vt 25165824                          ([bh][d][2048])
//   ctx 29360128                         ([m][1024])

typedef _Float16 f16;
typedef f16 f16x4 __attribute__((ext_vector_type(4)));
typedef f16 f16x8 __attribute__((ext_vector_type(8)));
typedef float f32x4 __attribute__((ext_vector_type(4)));
typedef uint32_t u32;
typedef u32 u32x4 __attribute__((ext_vector_type(4)));

#define L2E 1.4426950408889634f

__device__ __forceinline__ void gload16(const void* g, void* l) {
    __builtin_amdgcn_global_load_lds((__attribute__((address_space(1))) void*)g,
                                     (__attribute__((address_space(3))) void*)l,
                                     16, 0, 0);
}

// ---------------- prep: input cvt (blocks 0..12287) + weight transpose (12288..13311) ----------------
__global__ __launch_bounds__(256) void k_prep(const float* __restrict__ q,
                                              const float* __restrict__ k,
                                              const float* __restrict__ v,
                                              const float* __restrict__ w0,
                                              const float* __restrict__ w1,
                                              const float* __restrict__ w2,
                                              const float* __restrict__ w3,
                                              f16* __restrict__ dst,
                                              f16* __restrict__ wt)
{
    __shared__ f16 t[64][72];   // [n][k], padded (wtrans branch only)
    const int bid = blockIdx.x, tid = threadIdx.x;
    if (bid < 12288) {
        // input conversion f32 -> f16
        int z = bid >> 12;
        int bx = bid & 4095;
        const float* s = (z == 0) ? q : (z == 1) ? k : v;
        size_t i = (size_t)bx * 256 + tid;
        float4 f = ((const float4*)s)[i];
        f16x4 o = {(f16)f.x, (f16)f.y, (f16)f.z, (f16)f.w};
        *(f16x4*)(dst + (size_t)z * 4194304 + i * 4) = o;
        return;
    }
    // weight transpose+convert: W[k][n] f32 -> Wt[n][k] f16 (Wq scaled 0.125)
    int w = bid - 12288;                 // 0..1023
    int z = w >> 8;
    int rem = w & 255;
    int tx = rem & 15, ty = rem >> 4;
    const float* W = (z == 0) ? w0 : (z == 1) ? w1 : (z == 2) ? w2 : w3;
    const float ws = (z == 0) ? 0.125f : 1.0f;
    f16* outp = wt + (size_t)z * 1048576;
#pragma unroll
    for (int r4 = 0; r4 < 4; r4++) {
        int row = r4 * 16 + (tid >> 4);      // k local
        int col = (tid & 15) * 4;            // n local
        float4 f = *(const float4*)(W + (size_t)(ty * 64 + row) * 1024 + tx * 64 + col);
        t[col + 0][row] = (f16)(f.x * ws); t[col + 1][row] = (f16)(f.y * ws);
        t[col + 2][row] = (f16)(f.z * ws); t[col + 3][row] = (f16)(f.w * ws);
    }
    __syncthreads();
#pragma unroll
    for (int cc = 0; cc < 2; cc++) {
        int c = tid + cc * 256;
        int row = c >> 3, ch = c & 7;        // n local, 8-elem chunk of k
        f16x8 vv;
#pragma unroll
        for (int j = 0; j < 8; j++) vv[j] = t[row][ch * 8 + j];
        *(f16x8*)(outp + (size_t)(tx * 64 + row) * 1024 + ty * 64 + ch * 8) = vv;
    }
}

// ---------------- GEMM: C[M=4096][N=1024] = A[m][k] * Bt[n][k]^T + bias ----------------
// XCD-bijective swizzle: lin = x + 8y in [0,256); xcd = lin&7 owns 4 m-rows
// x 8 n-cols -> per-XCD L2 set = 4 A-panels (1MB) + full B (2MB) < 4MB.
__global__ __launch_bounds__(256) void k_gemm(const f16* __restrict__ Ab,
                                              const f16* __restrict__ Wtb,
                                              const float* __restrict__ b0,
                                              const float* __restrict__ b1,
                                              const float* __restrict__ b2,
                                              void* __restrict__ o0,
                                              void* __restrict__ o1,
                                              int proj)
{
    __shared__ __align__(16) char As[16384];  // [128 rows][128B = BK=64 f16]
    __shared__ __align__(16) char Bs[16384];
    const int tid = threadIdx.x;
    const int wv = tid >> 6, ln = tid & 63, lg = ln >> 4, li = ln & 15;
    const int lin = blockIdx.x + (blockIdx.y << 3);
    const int xcd = lin & 7, loc = lin >> 3;
    const int m0 = (xcd * 4 + (loc >> 3)) * 128;
    const int n0 = (loc & 7) * 128;
    const int wm = (wv >> 1) * 64, wn = (wv & 1) * 64;

    const f16* A; const f16* Bt; const float* bias; int mode; float bscale = 1.0f;
    if (proj) {
        int z = blockIdx.z;
        A = Ab + (size_t)z * 4194304;
        Bt = Wtb + (size_t)z * 1048576;
        bias = (z == 0) ? b0 : (z == 1) ? b1 : b2;
        if (z == 0) bscale = 0.125f;     // Wq was pre-scaled; match bias
        mode = (z == 2) ? 1 : 0;
    } else { A = Ab; Bt = Wtb; bias = b0; mode = 2; }

    const char* gA[4]; const char* gB[4];
#pragma unroll
    for (int c = 0; c < 4; c++) {
        int r = (wv * 4 + c) * 8 + (ln >> 3);
        int j = (ln & 7) ^ (r & 7);
        gA[c] = (const char*)A  + (size_t)(m0 + r) * 2048 + j * 16;
        gB[c] = (const char*)Bt + (size_t)(n0 + r) * 2048 + j * 16;
    }

    f32x4 acc[4][4] = {};
    for (int kt = 0; kt < 16; kt++) {
        __syncthreads();
#pragma unroll
        for (int c = 0; c < 4; c++) {
            gload16(gA[c] + kt * 128, As + (wv * 4 + c) * 1024);
            gload16(gB[c] + kt * 128, Bs + (wv * 4 + c) * 1024);
        }
        __syncthreads();
#pragma unroll
        for (int kk = 0; kk < 2; kk++) {
            f16x8 af[4], bf[4];
#pragma unroll
            for (int mi = 0; mi < 4; mi++) {
                int row = wm + mi * 16 + li;
                af[mi] = *(const f16x8*)(As + row * 128 + (((kk * 4 + lg) ^ (row & 7)) * 16));
            }
#pragma unroll
            for (int ni = 0; ni < 4; ni++) {
                int row = wn + ni * 16 + li;
                bf[ni] = *(const f16x8*)(Bs + row * 128 + (((kk * 4 + lg) ^ (row & 7)) * 16));
            }
#pragma unroll
            for (int mi = 0; mi < 4; mi++)
#pragma unroll
                for (int ni = 0; ni < 4; ni++)
                    acc[mi][ni] = __builtin_amdgcn_mfma_f32_16x16x32_f16(af[mi], bf[ni], acc[mi][ni], 0, 0, 0);
        }
    }

    float bvs[4];
#pragma unroll
    for (int ni = 0; ni < 4; ni++) bvs[ni] = bias[n0 + wn + ni * 16 + li] * bscale;

    if (mode == 2) {
        float* O = (float*)o0;
#pragma unroll
        for (int mi = 0; mi < 4; mi++)
#pragma unroll
            for (int ni = 0; ni < 4; ni++) {
                int n = n0 + wn + ni * 16 + li;
#pragma unroll
                for (int r = 0; r < 4; r++) {
                    int m = m0 + wm + mi * 16 + lg * 4 + r;
                    O[(size_t)m * 1024 + n] = acc[mi][ni][r] + bvs[ni];
                }
            }
    } else if (mode == 0) {
        f16* O = (f16*)o0 + (size_t)blockIdx.z * 4194304;  // Qb or Kb
#pragma unroll
        for (int mi = 0; mi < 4; mi++)
#pragma unroll
            for (int ni = 0; ni < 4; ni++) {
                int n = n0 + wn + ni * 16 + li;
                int h = n >> 6, d = n & 63;
#pragma unroll
                for (int r = 0; r < 4; r++) {
                    int m = m0 + wm + mi * 16 + lg * 4 + r;
                    int b = m >> 11, s = m & 2047;
                    O[(((size_t)b * 16 + h) * 2048 + s) * 64 + d] = (f16)(acc[mi][ni][r] + bvs[ni]);
                }
            }
    } else {
        f16* O = (f16*)o1;  // Vt [bh][d][2048]
#pragma unroll
        for (int mi = 0; mi < 4; mi++)
#pragma unroll
            for (int ni = 0; ni < 4; ni++) {
                int n = n0 + wn + ni * 16 + li;
                int h = n >> 6, d = n & 63;
                int mb = m0 + wm + mi * 16 + lg * 4;
                int b = mb >> 11, s = mb & 2047;
                f16x4 pk;
#pragma unroll
                for (int r = 0; r < 4; r++) pk[r] = (f16)(acc[mi][ni][r] + bvs[ni]);
                *(f16x4*)(O + (((size_t)b * 16 + h) * 64 + d) * 2048 + s) = pk;
            }
    }
}

// ---------------- attention (R13 champion; Q pre-scaled at prep) ----------------
// grid 1024 x 256 thr (4 waves, wave owns 16 q rows).
// bh = (bid&7)*4 + ((bid>>3)>>5): each XCD owns 4 heads (K+V 2MB, L2-resident).
// Pass 1: K staged in LDS, 128-kv tiles, l-sum only (no stores).
// Pass 2: K staged in LDS (64-kv, swizzled, depth-1 reg prefetch); V direct
// from L2; P -> wave-private LDS (f16, for PV); attn read back in transposed
// lane mapping -> nt f32x4 stores, 4 rows x 256B contiguous segments.
// Swapped QK^T: z = mfma(K,Q) -> lane holds P^T[kv][q], q=li lane-local.
__global__ __launch_bounds__(256, 4) void k_attn(const f16* __restrict__ Qb,
                                                 const f16* __restrict__ Kb,
                                                 const f16* __restrict__ Vt,
                                                 float* __restrict__ attn,
                                                 f16* __restrict__ ctx)
{
    __shared__ __align__(16) char Ks[16384];     // pass1: [128 kv][64 d]; pass2: [64 kv][64 d]
    __shared__ __align__(16) char Ps[4][2048];   // per-wave P [16 q][64 kv] f16, chunk^(row&7)
    const int tid = threadIdx.x, wv = tid >> 6, ln = tid & 63, lg = ln >> 4, li = ln & 15;
    const int bid = blockIdx.x;
    const int kk = bid >> 3;
    const int bh = (bid & 7) * 4 + (kk >> 5);
    const int q0 = (kk & 31) * 64 + wv * 16;

    const char* KbB = (const char*)Kb + (size_t)bh * 262144;  // 2048 kv x 128B
    const char* VtB = (const char*)Vt + (size_t)bh * 262144;  // 64 d x 4096B

    // Q fragment (B-operand), rows q0+li — already scaled by 1/sqrt(64) at prep
    const f16* qrow = Qb + ((size_t)bh * 2048 + q0 + li) * 64 + lg * 8;
    f16x8 aq0 = *(const f16x8*)(qrow);
    f16x8 aq1 = *(const f16x8*)(qrow + 32);

    // ================= pass 1: row sum of exp (128-kv tiles) =================
    float lacc[4] = {0.f, 0.f, 0.f, 0.f};
    {
        int swp[4];
        const char* gp[4];
#pragma unroll
        for (int t = 0; t < 4; t++) {
            int c = tid + t * 256;
            int r = c >> 3, j = c & 7;
            swp[t] = r * 128 + ((j ^ (r & 7)) * 16);
            gp[t] = KbB + (size_t)r * 128 + j * 16;
        }
        u32x4 s[4];
#pragma unroll
        for (int t = 0; t < 4; t++) s[t] = *(const u32x4*)(gp[t]);
        for (int kt = 0; kt < 16; kt++) {
            __syncthreads();
#pragma unroll
            for (int t = 0; t < 4; t++) *(u32x4*)(Ks + swp[t]) = s[t];
            __syncthreads();
            if (kt + 1 < 16) {
#pragma unroll
                for (int t = 0; t < 4; t++) s[t] = *(const u32x4*)(gp[t] + (size_t)(kt + 1) * 16384);
            }
#pragma unroll
            for (int cf = 0; cf < 8; cf++) {
                int row = cf * 16 + li;
                f16x8 ak0 = *(const f16x8*)(Ks + row * 128 + ((lg ^ (row & 7)) * 16));
                f16x8 ak1 = *(const f16x8*)(Ks + row * 128 + (((4 + lg) ^ (row & 7)) * 16));
                f32x4 z = {0.f, 0.f, 0.f, 0.f};
                z = __builtin_amdgcn_mfma_f32_16x16x32_f16(ak0, aq0, z, 0, 0, 0);
                z = __builtin_amdgcn_mfma_f32_16x16x32_f16(ak1, aq1, z, 0, 0, 0);
                lacc[cf & 3] += exp2f(z[0] * L2E) + exp2f(z[1] * L2E)
                              + exp2f(z[2] * L2E) + exp2f(z[3] * L2E);
            }
        }
    }
    float l_ = (lacc[0] + lacc[1]) + (lacc[2] + lacc[3]);
    l_ += __shfl_xor(l_, 16);
    l_ += __shfl_xor(l_, 32);
    const float inv_l = 1.0f / l_;
    float* aBase = attn + ((size_t)bh * 2048 + q0) * 2048;
    char* Pw = Ps[wv];

    // coalesced store lane mapping (constant over kt):
    //   instruction j: row = j*4 + (ln>>4), kv = (ln&15)*4
    const int srowb = ln >> 4;                 // 0..3
    const int skv = (ln & 15) * 4;             // 0..60
    const int sldso = (((ln & 15) >> 1) * 16) + (ln & 1) * 8;  // chunk*16 + half

    // ================= pass 2: P, attn out, PV (64-kv tiles) =================
    f32x4 cacc[4] = {};   // ctx^T frags: q=li, d=df*16+lg*4+r
    const int r0 = tid >> 3, j0 = tid & 7;
    const int r1 = (tid + 256) >> 3, j1 = (tid + 256) & 7;
    const int sw0 = r0 * 128 + ((j0 ^ (r0 & 7)) * 16);
    const int sw1 = r1 * 128 + ((j1 ^ (r1 & 7)) * 16);
    u32x4 sk0 = *(const u32x4*)(KbB + (size_t)r0 * 128 + j0 * 16);
    u32x4 sk1 = *(const u32x4*)(KbB + (size_t)r1 * 128 + j1 * 16);
    for (int kt = 0; kt < 32; kt++) {
        __syncthreads();
        *(u32x4*)(Ks + sw0) = sk0;
        *(u32x4*)(Ks + sw1) = sk1;
        __syncthreads();
        if (kt + 1 < 32) {
            sk0 = *(const u32x4*)(KbB + (size_t)((kt + 1) * 64 + r0) * 128 + j0 * 16);
            sk1 = *(const u32x4*)(KbB + (size_t)((kt + 1) * 64 + r1) * 128 + j1 * 16);
        }
        // V fragments direct from global/L2 (issued early; latency hides under QK^T)
        f16x8 vf[4][2];
#pragma unroll
        for (int df = 0; df < 4; df++) {
            const char* vr = VtB + (size_t)(df * 16 + li) * 4096 + kt * 128 + lg * 16;
            vf[df][0] = *(const f16x8*)vr;
            vf[df][1] = *(const f16x8*)(vr + 64);
        }
        // QK^T from LDS
        f32x4 zz[4];
#pragma unroll
        for (int cf = 0; cf < 4; cf++) {
            int row = cf * 16 + li;
            f16x8 ak0 = *(const f16x8*)(Ks + row * 128 + ((lg ^ (row & 7)) * 16));
            f16x8 ak1 = *(const f16x8*)(Ks + row * 128 + (((4 + lg) ^ (row & 7)) * 16));
            f32x4 z = {0.f, 0.f, 0.f, 0.f};
            z = __builtin_amdgcn_mfma_f32_16x16x32_f16(ak0, aq0, z, 0, 0, 0);
            z = __builtin_amdgcn_mfma_f32_16x16x32_f16(ak1, aq1, z, 0, 0, 0);
            zz[cf] = z;
        }
        // exp -> P pack into wave-private LDS (f16, swizzled)
#pragma unroll
        for (int cf = 0; cf < 4; cf++) {
            float p0 = exp2f(zz[cf][0] * L2E) * inv_l;
            float p1 = exp2f(zz[cf][1] * L2E) * inv_l;
            float p2 = exp2f(zz[cf][2] * L2E) * inv_l;
            float p3 = exp2f(zz[cf][3] * L2E) * inv_l;
            f16x4 pk = {(f16)p0, (f16)p1, (f16)p2, (f16)p3};
            int c = cf * 2 + (lg >> 1);
            *(f16x4*)(Pw + li * 128 + ((c ^ (li & 7)) * 16) + (lg & 1) * 8) = pk;
        }
        // attn store: LDS readback in transposed lane mapping -> 256B segments
#pragma unroll
        for (int j = 0; j < 4; j++) {
            int row = j * 4 + srowb;
            f16x4 pv4 = *(const f16x4*)(Pw + row * 128 + (sldso ^ ((row & 7) * 16)));
            f32x4 fv = {(float)pv4[0], (float)pv4[1], (float)pv4[2], (float)pv4[3]};
            __builtin_nontemporal_store(fv, (f32x4*)(aBase + (size_t)row * 2048 + kt * 64 + skv));
        }
        // PV: ctx^T += V^T * P^T
#pragma unroll
        for (int s2 = 0; s2 < 2; s2++) {
            f16x8 bp = *(const f16x8*)(Pw + li * 128 + (((s2 * 4 + lg) ^ (li & 7)) * 16));
#pragma unroll
            for (int df = 0; df < 4; df++)
                cacc[df] = __builtin_amdgcn_mfma_f32_16x16x32_f16(vf[df][s2], bp, cacc[df], 0, 0, 0);
        }
    }

    // ctx write: [m = b*2048+s][n = h*64+d]
    const int b = bh >> 4, h = bh & 15;
#pragma unroll
    for (int df = 0; df < 4; df++) {
        f16x4 pk;
#pragma unroll
        for (int r = 0; r < 4; r++) pk[r] = (f16)cacc[df][r];
        size_t mrow = (size_t)b * 2048 + q0 + li;
        size_t n = (size_t)h * 64 + df * 16 + lg * 4;
        *(f16x4*)(ctx + mrow * 1024 + n) = pk;
    }
}

extern "C" void kernel_launch(void* const* d_in, const int* in_sizes, int n_in,
                              void* d_out, int out_size, void* d_ws, size_t ws_size,
                              hipStream_t stream)
{
    const float* q  = (const float*)d_in[0];
    const float* k  = (const float*)d_in[1];
    const float* v  = (const float*)d_in[2];
    const float* Wq = (const float*)d_in[3];
    const float* bq = (const float*)d_in[4];
    const float* Wk = (const float*)d_in[5];
    const float* bk = (const float*)d_in[6];
    const float* Wv = (const float*)d_in[7];
    const float* bv = (const float*)d_in[8];
    const float* Wo = (const float*)d_in[9];
    const float* bo = (const float*)d_in[10];

    f16* W = (f16*)d_ws;
    float* out = (float*)d_out;
    float* attn = out + 4194304;

    f16* X   = W;                 // 3 x 4194304
    f16* Wt  = W + 12582912;      // 4 x 1048576
    f16* QKb = W + 16777216;      // Qb then Kb
    f16* Vt  = W + 25165824;
    f16* ctx = W + 29360128;

    k_prep<<<dim3(13312), 256, 0, stream>>>(q, k, v, Wq, Wk, Wv, Wo, X, Wt);
    k_gemm<<<dim3(8, 32, 3), 256, 0, stream>>>(X, Wt, bq, bk, bv, QKb, Vt, 1);
    k_attn<<<dim3(1024), 256, 0, stream>>>(QKb, QKb + 4194304, Vt, attn, ctx);
    k_gemm<<<dim3(8, 32, 1), 256, 0, stream>>>(ctx, Wt + 3145728, bo, bo, bo, out, nullptr, 0);
}